// Round 2
// baseline (551.027 us; speedup 1.0000x reference)
//
#include <hip/hip_runtime.h>
#include <hip/hip_bf16.h>

#define N_NODES 8192
#define IN_F 512
#define OUT_F 128
#define KPARTS 4
#define LOG2E 1.4426950408889634f

typedef unsigned short u16;
typedef short s16x8 __attribute__((ext_vector_type(8)));
typedef float f32x4 __attribute__((ext_vector_type(4)));

union BF8 { s16x8 v; u16 u[8]; };

__device__ __forceinline__ u16 f2bf(float f) {
    union { float f; unsigned u; } x; x.f = f;
    unsigned r = x.u + 0x7FFFu + ((x.u >> 16) & 1u);
    return (u16)(r >> 16);
}
__device__ __forceinline__ float bf2f(u16 u) {
    union { unsigned u; float f; } x; x.u = ((unsigned)u) << 16;
    return x.f;
}

// K0: repack W [512x128] fp32 -> bf16 MFMA B-fragment layout:
// W_frag[((kt*8+nt)*64+lane)*8+j] = bf16(W[kt*32+(lane>>4)*8+j][nt*16+(lane&15)])
__global__ void repack_W(const float* __restrict__ W, u16* __restrict__ W_frag) {
    int tid = blockIdx.x * 256 + threadIdx.x;   // 0..65535
    int j = tid & 7;
    int lane = (tid >> 3) & 63;
    int nt = (tid >> 9) & 7;
    int kt = tid >> 12;
    int k = kt * 32 + (lane >> 4) * 8 + j;
    int n = nt * 16 + (lane & 15);
    W_frag[tid] = f2bf(W[k * OUT_F + n]);
}

// K1: h = X@W via 16x16x32 bf16 MFMA (X fp32 -> bf16 in-register).
// Also Wh1 = h@a1, Wh2 = h@a2 (fp32), and scatter h (bf16) into
// B-fragment layout h_frag for the attention matmul.
// grid 128 blocks x 256 thr (4 waves); block does 64 rows x 128 cols.
__global__ __launch_bounds__(256)
void gemm_h(const float* __restrict__ X, const u16* __restrict__ W_frag,
            const float* __restrict__ a1, const float* __restrict__ a2,
            float* __restrict__ Wh1, float* __restrict__ Wh2,
            u16* __restrict__ h_frag) {
    int tid = threadIdx.x;
    int wave = tid >> 6;
    int lane = tid & 63;
    int quad = lane >> 4;
    int lid = lane & 15;
    int rbase = blockIdx.x * 64 + wave * 16;

    f32x4 acc[8] = {};
    const s16x8* Wf = (const s16x8*)W_frag;
    int rA = rbase + lid;
    const float* xrow = X + (size_t)rA * IN_F;

    for (int kt = 0; kt < 16; kt++) {
        float4 x0 = *(const float4*)(xrow + kt * 32 + quad * 8);
        float4 x1 = *(const float4*)(xrow + kt * 32 + quad * 8 + 4);
        BF8 a;
        a.u[0] = f2bf(x0.x); a.u[1] = f2bf(x0.y); a.u[2] = f2bf(x0.z); a.u[3] = f2bf(x0.w);
        a.u[4] = f2bf(x1.x); a.u[5] = f2bf(x1.y); a.u[6] = f2bf(x1.z); a.u[7] = f2bf(x1.w);
        #pragma unroll
        for (int nt = 0; nt < 8; nt++) {
            s16x8 b = Wf[(kt * 8 + nt) * 64 + lane];
            acc[nt] = __builtin_amdgcn_mfma_f32_16x16x32_bf16(a.v, b, acc[nt], 0, 0, 0);
        }
    }

    float a1v[8], a2v[8];
    #pragma unroll
    for (int nt = 0; nt < 8; nt++) {
        a1v[nt] = a1[nt * 16 + lid];
        a2v[nt] = a2[nt * 16 + lid];
    }

    // C/D layout: row = quad*4+reg, col = nt*16+lid
    #pragma unroll
    for (int reg = 0; reg < 4; reg++) {
        int row = rbase + quad * 4 + reg;
        float p1 = 0.f, p2 = 0.f;
        #pragma unroll
        for (int nt = 0; nt < 8; nt++) {
            float h = acc[nt][reg];
            p1 += h * a1v[nt];
            p2 += h * a2v[nt];
            // scatter into B-fragment layout (k = row, n = nt*16+lid)
            int ktile = row >> 5;
            int kl = row & 31;
            int lane2 = (kl >> 3) * 16 + lid;
            int j2 = kl & 7;
            h_frag[(size_t)((ktile * 8 + nt) * 64 + lane2) * 8 + j2] = f2bf(h);
        }
        #pragma unroll
        for (int m = 1; m < 16; m <<= 1) {
            p1 += __shfl_xor(p1, m, 64);
            p2 += __shfl_xor(p2, m, 64);
        }
        if (lid == 0) { Wh1[row] = p1; Wh2[row] = p2; }
    }
}

// K2: fused mask + sigmoid + exp + P@h. P built in registers in MFMA
// A-fragment layout (A[m=lane&15][k=quad*8+j]); no LDS, no barriers.
// grid = 128 row-tiles x KPARTS k-parts, 256 thr (4 waves x 16 rows).
__global__ __launch_bounds__(256)
void attn_kernel(const int* __restrict__ adj, const float* __restrict__ Wh1,
                 const float* __restrict__ Wh2, const u16* __restrict__ h_frag,
                 float* __restrict__ out_part, float* __restrict__ sum_part) {
    int tid = threadIdx.x;
    int wave = tid >> 6;
    int lane = tid & 63;
    int quad = lane >> 4;
    int lid = lane & 15;
    int rtile = blockIdx.x >> 2;
    int kh = blockIdx.x & (KPARTS - 1);
    int rbase = rtile * 64 + wave * 16;
    int r = rbase + lid;

    float wh1r = Wh1[r];
    f32x4 acc[8] = {};
    float psum = 0.f;

    const s16x8* Hf = (const s16x8*)h_frag;
    const int* adjrow = adj + (size_t)r * N_NODES;

    const int KT_PER = 256 / KPARTS;       // 64 k-tiles of 32 columns
    int kt0 = kh * KT_PER;
    for (int kt = kt0; kt < kt0 + KT_PER; kt++) {
        int k0 = kt * 32 + quad * 8;
        int4 aj0 = *(const int4*)(adjrow + k0);
        int4 aj1 = *(const int4*)(adjrow + k0 + 4);
        float4 w20 = *(const float4*)(Wh2 + k0);
        float4 w21 = *(const float4*)(Wh2 + k0 + 4);
        float w2[8] = {w20.x, w20.y, w20.z, w20.w, w21.x, w21.y, w21.z, w21.w};
        int aj[8] = {aj0.x, aj0.y, aj0.z, aj0.w, aj1.x, aj1.y, aj1.z, aj1.w};
        BF8 af;
        #pragma unroll
        for (int j = 0; j < 8; j++) {
            float alpha = wh1r + w2[j];
            float e = exp2f(-LOG2E * alpha);             // exp(-alpha)
            float s = __builtin_amdgcn_rcpf(1.0f + e);   // sigmoid(alpha)
            float p = exp2f(LOG2E * s);                  // exp(sigmoid)
            u16 pb = f2bf(p);
            pb = (aj[j] > 0) ? pb : (u16)0;
            af.u[j] = pb;
            psum += bf2f(pb);   // denominator consistent with bf16 numerator
        }
        #pragma unroll
        for (int nt = 0; nt < 8; nt++) {
            s16x8 b = Hf[(kt * 8 + nt) * 64 + lane];
            acc[nt] = __builtin_amdgcn_mfma_f32_16x16x32_bf16(af.v, b, acc[nt], 0, 0, 0);
        }
    }

    // psum: lanes {lid, lid+16, lid+32, lid+48} hold partials for row r
    psum += __shfl_xor(psum, 16, 64);
    psum += __shfl_xor(psum, 32, 64);
    if (quad == 0) sum_part[(size_t)kh * N_NODES + r] = psum;

    #pragma unroll
    for (int nt = 0; nt < 8; nt++) {
        #pragma unroll
        for (int reg = 0; reg < 4; reg++) {
            int row = rbase + quad * 4 + reg;
            int col = nt * 16 + lid;
            out_part[((size_t)kh * N_NODES + row) * OUT_F + col] = acc[nt][reg];
        }
    }
}

// K3: out = (sum_k part_k) / (sum_k rowsum_k), fp32 output
__global__ void finalize(const float* __restrict__ out_part,
                         const float* __restrict__ sum_part,
                         float* __restrict__ out) {
    int gid = blockIdx.x * 256 + threadIdx.x;   // 0 .. 1048575
    int i = gid >> 7;
    float s = 0.f, v = 0.f;
    #pragma unroll
    for (int kh = 0; kh < KPARTS; kh++) {
        s += sum_part[kh * N_NODES + i];
        v += out_part[(size_t)kh * N_NODES * OUT_F + gid];
    }
    out[gid] = v / s;
}

extern "C" void kernel_launch(void* const* d_in, const int* in_sizes, int n_in,
                              void* d_out, int out_size, void* d_ws, size_t ws_size,
                              hipStream_t stream) {
    const float* X   = (const float*)d_in[0];
    const int*   adj = (const int*)d_in[1];
    const float* W   = (const float*)d_in[2];
    const float* a1  = (const float*)d_in[3];
    const float* a2  = (const float*)d_in[4];

    char* ws = (char*)d_ws;
    float* Wh1      = (float*)(ws);                                  // 32 KB
    float* Wh2      = (float*)(ws + (32 << 10));                     // 32 KB
    u16*   W_frag   = (u16*)  (ws + (64 << 10));                     // 128 KB
    u16*   h_frag   = (u16*)  (ws + (192 << 10));                    // 2 MB
    float* out_part = (float*)(ws + (192 << 10) + (2 << 20));        // KPARTS*4 MB
    float* sum_part = (float*)(ws + (192 << 10) + (2 << 20) + (size_t)KPARTS * N_NODES * OUT_F * 4);
    float* out      = (float*)d_out;

    hipLaunchKernelGGL(repack_W, dim3(256), dim3(256), 0, stream, W, W_frag);
    hipLaunchKernelGGL(gemm_h, dim3(128), dim3(256), 0, stream,
                       X, W_frag, a1, a2, Wh1, Wh2, h_frag);
    hipLaunchKernelGGL(attn_kernel, dim3(128 * KPARTS), dim3(256), 0, stream,
                       adj, Wh1, Wh2, h_frag, out_part, sum_part);
    hipLaunchKernelGGL(finalize, dim3((N_NODES * OUT_F) / 256), dim3(256), 0, stream,
                       out_part, sum_part, out);
}

// Round 5
// 439.916 us; speedup vs baseline: 1.2526x; 1.2526x over previous
//
#include <hip/hip_runtime.h>
#include <hip/hip_bf16.h>

#define N_NODES 8192
#define IN_F 512
#define OUT_F 128
#define LOG2E 1.4426950408889634f

typedef unsigned short u16;
typedef unsigned int u32;
typedef short s16x8 __attribute__((ext_vector_type(8)));
typedef float f32x4 __attribute__((ext_vector_type(4)));
typedef u32 u32x4 __attribute__((ext_vector_type(4)));

__device__ __forceinline__ u16 f2bf(float f) {
    union { float f; unsigned u; } x; x.f = f;
    unsigned r = x.u + 0x7FFFu + ((x.u >> 16) & 1u);
    return (u16)(r >> 16);
}

// pack two floats into one u32 as (bf16(b)<<16) | bf16(a)
__device__ __forceinline__ u32 packbf2(float a, float b) {
    return ((u32)f2bf(b) << 16) | (u32)f2bf(a);
}

// edge weight: exp(sigmoid(alpha)) or 0 if masked
__device__ __forceinline__ float edge_p(float wh1, float w2, int keep) {
    float alpha = wh1 + w2;
    float e = exp2f(-LOG2E * alpha);
    float s = __builtin_amdgcn_rcpf(1.0f + e);
    float p = exp2f(LOG2E * s);
    return keep ? p : 0.0f;
}

// pack pair to bf16, accumulate bf16-rounded values into psum
__device__ __forceinline__ u32 pack_p(float p0, float p1, float& psum) {
    u32 u = packbf2(p0, p1);
    union { u32 u; float f; } lo, hi;
    lo.u = u << 16;
    hi.u = u & 0xFFFF0000u;
    psum += lo.f + hi.f;
    return u;
}

// ---- K0: repack W [512x128] fp32 -> bf16 MFMA B-fragment layout
__global__ void repack_W(const float* __restrict__ W, u16* __restrict__ W_frag) {
    int tid = blockIdx.x * 256 + threadIdx.x;   // 0..65535
    int j = tid & 7;
    int lane = (tid >> 3) & 63;
    int nt = (tid >> 9) & 7;
    int kt = tid >> 12;
    int k = kt * 32 + (lane >> 4) * 8 + j;
    int n = nt * 16 + (lane & 15);
    W_frag[tid] = f2bf(W[k * OUT_F + n]);
}

// ---- Wa1 = W@a1, Wa2 = W@a2 (fp32, 512 each)
__global__ void compute_Wa(const float* __restrict__ W, const float* __restrict__ a1,
                           const float* __restrict__ a2,
                           float* __restrict__ Wa1, float* __restrict__ Wa2) {
    int k = blockIdx.x * 256 + threadIdx.x;
    if (k >= IN_F) return;
    float s1 = 0.f, s2 = 0.f;
    for (int n = 0; n < OUT_F; n++) {
        float w = W[k * OUT_F + n];
        s1 += w * a1[n];
        s2 += w * a2[n];
    }
    Wa1[k] = s1; Wa2[k] = s2;
}

// ---- K1: h = X@W (bf16 MFMA), scatter h into B-fragment layout; Wh = X@Wa (fp32).
// grid 512 blocks x 256 thr; block = 16 rows; wave w handles nt = 2w, 2w+1.
__global__ __launch_bounds__(256)
void gemm_h(const float* __restrict__ X, const u16* __restrict__ W_frag,
            const float* __restrict__ Wa1, const float* __restrict__ Wa2,
            float* __restrict__ Wh1, float* __restrict__ Wh2,
            u16* __restrict__ h_frag) {
    int tid = threadIdx.x;
    int wave = tid >> 6;
    int lane = tid & 63;
    int quad = lane >> 4;
    int lid = lane & 15;
    int rbase = blockIdx.x * 16;
    const float* xrow = X + (size_t)(rbase + lid) * IN_F;
    const s16x8* Wf = (const s16x8*)W_frag;
    f32x4 acc0 = {}, acc1 = {};
    float p1 = 0.f, p2 = 0.f;
    int nt0 = wave * 2;

    for (int kt = 0; kt < 16; kt++) {
        float4 x0 = *(const float4*)(xrow + kt * 32 + quad * 8);
        float4 x1 = *(const float4*)(xrow + kt * 32 + quad * 8 + 4);
        u32x4 uv;
        uv.x = packbf2(x0.x, x0.y); uv.y = packbf2(x0.z, x0.w);
        uv.z = packbf2(x1.x, x1.y); uv.w = packbf2(x1.z, x1.w);
        s16x8 a = __builtin_bit_cast(s16x8, uv);
        if (wave == 0) {
            float4 wa = *(const float4*)(Wa1 + kt * 32 + quad * 8);
            float4 wb = *(const float4*)(Wa1 + kt * 32 + quad * 8 + 4);
            float4 wc = *(const float4*)(Wa2 + kt * 32 + quad * 8);
            float4 wd = *(const float4*)(Wa2 + kt * 32 + quad * 8 + 4);
            p1 += x0.x*wa.x + x0.y*wa.y + x0.z*wa.z + x0.w*wa.w
                + x1.x*wb.x + x1.y*wb.y + x1.z*wb.z + x1.w*wb.w;
            p2 += x0.x*wc.x + x0.y*wc.y + x0.z*wc.z + x0.w*wc.w
                + x1.x*wd.x + x1.y*wd.y + x1.z*wd.z + x1.w*wd.w;
        }
        s16x8 b0 = Wf[(kt * 8 + nt0) * 64 + lane];
        s16x8 b1 = Wf[(kt * 8 + nt0 + 1) * 64 + lane];
        acc0 = __builtin_amdgcn_mfma_f32_16x16x32_bf16(a, b0, acc0, 0, 0, 0);
        acc1 = __builtin_amdgcn_mfma_f32_16x16x32_bf16(a, b1, acc1, 0, 0, 0);
    }

    // scatter h (C/D layout: row=quad*4+reg, col=nt*16+lid) into B-fragment layout
    #pragma unroll
    for (int reg = 0; reg < 4; reg++) {
        int row = rbase + quad * 4 + reg;
        int ktile = row >> 5, kl = row & 31;
        int lane2 = (kl >> 3) * 16 + lid, j2 = kl & 7;
        h_frag[(size_t)((ktile * 8 + nt0) * 64 + lane2) * 8 + j2] = f2bf(acc0[reg]);
        h_frag[(size_t)((ktile * 8 + nt0 + 1) * 64 + lane2) * 8 + j2] = f2bf(acc1[reg]);
    }
    if (wave == 0) {
        p1 += __shfl_xor(p1, 16, 64); p1 += __shfl_xor(p1, 32, 64);
        p2 += __shfl_xor(p2, 16, 64); p2 += __shfl_xor(p2, 32, 64);
        if (lane < 16) { Wh1[rbase + lid] = p1; Wh2[rbase + lid] = p2; }
    }
}

// ---- K2: fused mask+sigmoid+exp+P@h, reads adj DIRECTLY (each element exactly
// once across the grid). 32 rows/wave (2 A-tiles), block = 128 rows;
// grid = 64 rtiles x KP kparts; KT_PER = 256>>kshift.
__global__ __launch_bounds__(256)
void attn_kernel(const int* __restrict__ adj, const float* __restrict__ Wh1,
                 const float* __restrict__ Wh2, const u16* __restrict__ h_frag,
                 float* __restrict__ out_part, float* __restrict__ sum_part,
                 int kshift) {
    int tid = threadIdx.x;
    int wave = tid >> 6;
    int lane = tid & 63;
    int quad = lane >> 4;
    int lid = lane & 15;
    int rtile = blockIdx.x >> kshift;
    int kh = blockIdx.x & ((1 << kshift) - 1);
    int rbase = rtile * 128 + wave * 32;
    int r0 = rbase + lid, r1 = r0 + 16;

    float wh10 = Wh1[r0], wh11 = Wh1[r1];
    f32x4 acc0[8] = {}, acc1[8] = {};
    float ps0 = 0.f, ps1 = 0.f;
    const s16x8* Hf = (const s16x8*)h_frag;
    const int* adjrow0 = adj + (size_t)r0 * N_NODES;
    const int* adjrow1 = adj + (size_t)r1 * N_NODES;

    int KT_PER = 256 >> kshift;
    int kt0 = kh * KT_PER;
    for (int kt = kt0; kt < kt0 + KT_PER; kt++) {
        int k0 = kt * 32 + quad * 8;
        int4 aj0a = *(const int4*)(adjrow0 + k0);
        int4 aj0b = *(const int4*)(adjrow0 + k0 + 4);
        int4 aj1a = *(const int4*)(adjrow1 + k0);
        int4 aj1b = *(const int4*)(adjrow1 + k0 + 4);
        float4 w20 = *(const float4*)(Wh2 + k0);
        float4 w21 = *(const float4*)(Wh2 + k0 + 4);

        u32x4 uv0, uv1;
        uv0.x = pack_p(edge_p(wh10, w20.x, aj0a.x), edge_p(wh10, w20.y, aj0a.y), ps0);
        uv0.y = pack_p(edge_p(wh10, w20.z, aj0a.z), edge_p(wh10, w20.w, aj0a.w), ps0);
        uv0.z = pack_p(edge_p(wh10, w21.x, aj0b.x), edge_p(wh10, w21.y, aj0b.y), ps0);
        uv0.w = pack_p(edge_p(wh10, w21.z, aj0b.z), edge_p(wh10, w21.w, aj0b.w), ps0);
        uv1.x = pack_p(edge_p(wh11, w20.x, aj1a.x), edge_p(wh11, w20.y, aj1a.y), ps1);
        uv1.y = pack_p(edge_p(wh11, w20.z, aj1a.z), edge_p(wh11, w20.w, aj1a.w), ps1);
        uv1.z = pack_p(edge_p(wh11, w21.x, aj1b.x), edge_p(wh11, w21.y, aj1b.y), ps1);
        uv1.w = pack_p(edge_p(wh11, w21.z, aj1b.z), edge_p(wh11, w21.w, aj1b.w), ps1);
        s16x8 af0 = __builtin_bit_cast(s16x8, uv0);
        s16x8 af1 = __builtin_bit_cast(s16x8, uv1);

        #pragma unroll
        for (int nt = 0; nt < 8; nt++) {
            s16x8 b = Hf[(kt * 8 + nt) * 64 + lane];
            acc0[nt] = __builtin_amdgcn_mfma_f32_16x16x32_bf16(af0, b, acc0[nt], 0, 0, 0);
            acc1[nt] = __builtin_amdgcn_mfma_f32_16x16x32_bf16(af1, b, acc1[nt], 0, 0, 0);
        }
    }

    ps0 += __shfl_xor(ps0, 16, 64); ps0 += __shfl_xor(ps0, 32, 64);
    ps1 += __shfl_xor(ps1, 16, 64); ps1 += __shfl_xor(ps1, 32, 64);
    if (quad == 0) {
        sum_part[(size_t)kh * N_NODES + r0] = ps0;
        sum_part[(size_t)kh * N_NODES + r1] = ps1;
    }

    #pragma unroll
    for (int nt = 0; nt < 8; nt++) {
        #pragma unroll
        for (int reg = 0; reg < 4; reg++) {
            int row0 = rbase + quad * 4 + reg;
            int col = nt * 16 + lid;
            out_part[((size_t)kh * N_NODES + row0) * OUT_F + col] = acc0[nt][reg];
            out_part[((size_t)kh * N_NODES + row0 + 16) * OUT_F + col] = acc1[nt][reg];
        }
    }
}

// ---- K3: out = (sum_k part_k) / (sum_k rowsum_k)
__global__ void finalize(const float* __restrict__ out_part,
                         const float* __restrict__ sum_part,
                         float* __restrict__ out, int kp) {
    int gid = blockIdx.x * 256 + threadIdx.x;
    int i = gid >> 7;
    float s = 0.f, v = 0.f;
    for (int kh = 0; kh < kp; kh++) {
        s += sum_part[(size_t)kh * N_NODES + i];
        v += out_part[(size_t)kh * N_NODES * OUT_F + gid];
    }
    out[gid] = v / s;
}

extern "C" void kernel_launch(void* const* d_in, const int* in_sizes, int n_in,
                              void* d_out, int out_size, void* d_ws, size_t ws_size,
                              hipStream_t stream) {
    const float* X   = (const float*)d_in[0];
    const int*   adj = (const int*)d_in[1];
    const float* W   = (const float*)d_in[2];
    const float* a1  = (const float*)d_in[3];
    const float* a2  = (const float*)d_in[4];

    // pick largest KPARTS (8..1) that fits ws
    const size_t BASE = (size_t)4 << 20;   // fixed region: Wh/Wa/W_frag/h_frag
    int kshift = 3;
    for (; kshift > 0; kshift--) {
        size_t kp = (size_t)1 << kshift;
        size_t need = BASE + kp * ((size_t)N_NODES * OUT_F * 4 + (size_t)N_NODES * 4);
        if (need <= ws_size) break;
    }
    int kp = 1 << kshift;

    char* ws = (char*)d_ws;
    float* Wh1 = (float*)(ws);                         // 32 KB
    float* Wh2 = (float*)(ws + (32 << 10));            // 32 KB
    float* Wa1 = (float*)(ws + (64 << 10));            // 2 KB
    float* Wa2 = (float*)(ws + (66 << 10));            // 2 KB
    u16* W_frag = (u16*)(ws + (128 << 10));            // 128 KB
    u16* h_frag = (u16*)(ws + (256 << 10));            // 2 MB  (ends at 2.25 MB < 4 MB)
    float* out_part = (float*)(ws + BASE);             // kp * 4 MB
    float* sum_part = (float*)(ws + BASE + ((size_t)kp << 22));  // kp * 32 KB
    float* out = (float*)d_out;

    hipLaunchKernelGGL(repack_W, dim3(256), dim3(256), 0, stream, W, W_frag);
    hipLaunchKernelGGL(compute_Wa, dim3(2), dim3(256), 0, stream, W, a1, a2, Wa1, Wa2);
    hipLaunchKernelGGL(gemm_h, dim3(512), dim3(256), 0, stream,
                       X, W_frag, Wa1, Wa2, Wh1, Wh2, h_frag);
    hipLaunchKernelGGL(attn_kernel, dim3(64 << kshift), dim3(256), 0, stream,
                       adj, Wh1, Wh2, h_frag, out_part, sum_part, kshift);
    hipLaunchKernelGGL(finalize, dim3((N_NODES * OUT_F) / 256), dim3(256), 0, stream,
                       out_part, sum_part, out, kp);
}